// Round 8
// baseline (79.850 us; speedup 1.0000x reference)
//
#include <hip/hip_runtime.h>
#include <hip/hip_cooperative_groups.h>
#include <math.h>

namespace cg = cooperative_groups;

#define NG 1024          // N_GAUSS (power of two)
#define LOG2E 1.4426950408889634f

// grec[i]  = {depth_bits, idx, tile_range(tx0|tx1<<8|ty0<<16|ty1<<24), 0}
// rec[i*3] = r0=(px,py,A2,B2) r1=(C2,op,cr,cg) r2=(cb,0,0,0)
// power_log2 = A2*dx^2 + C2*dy^2 + B2*dx*dy   (A2 = -0.5*log2e*A, etc.)

__device__ inline unsigned long long bstage_shfl(unsigned long long key,
                                                 int tid, int j, int k) {
    unsigned long long partner = __shfl_xor(key, j, 64);
    bool lower = (tid & j) == 0;
    bool asc   = (tid & k) == 0;
    return ((key < partner) == (lower == asc)) ? key : partner;
}

__device__ inline float rlane(float v, int l) {
    return __int_as_float(__builtin_amdgcn_readlane(__float_as_int(v), l));
}

// Single cooperative kernel: blocks 0..15 prep all gaussians, grid sync,
// then every block rasterizes one 8x8 tile.
__global__ void __launch_bounds__(64) fused_kernel(
    const float* __restrict__ means3D, const float* __restrict__ opacities,
    const float* __restrict__ scales,  const float* __restrict__ rotations,
    const float* __restrict__ shs,     const float* __restrict__ view_mat,
    const float* __restrict__ proj_mat,const float* __restrict__ cam_pos,
    const float* __restrict__ tanx_p,  const float* __restrict__ tany_p,
    const int* __restrict__ h_p,       const int* __restrict__ w_p,
    uint4* __restrict__ grec, float4* __restrict__ rec,
    const float* __restrict__ background, float* __restrict__ out,
    int N, int W, int HW)
{
    __shared__ unsigned long long skey[NG];
    int blk  = blockIdx.x;
    int lane = threadIdx.x;

    // ================= phase A: preprocess (blocks 0..15) =================
    int i = blk * 64 + lane;
    if (blk < (N + 63) / 64 && i < N) {
        float tanx = tanx_p[0], tany = tany_p[0];
        float Wf = (float)w_p[0], Hf = (float)h_p[0];
        int tilesX = w_p[0] >> 3, tilesY = h_p[0] >> 3;
        float fx = Wf / (2.f * tanx), fy = Hf / (2.f * tany);

        float mx = means3D[3*i], my = means3D[3*i+1], mz = means3D[3*i+2];

        float4 q4 = ((const float4*)rotations)[i];
        float qr = q4.x, qx = q4.y, qy = q4.z, qz = q4.w;
        float qn = sqrtf(qr*qr + qx*qx + qy*qy + qz*qz);
        qr /= qn; qx /= qn; qy /= qn; qz /= qn;
        float sx = scales[3*i], sy = scales[3*i+1], sz = scales[3*i+2];
        float R00 = 1.f-2.f*(qy*qy+qz*qz), R01 = 2.f*(qx*qy-qr*qz), R02 = 2.f*(qx*qz+qr*qy);
        float R10 = 2.f*(qx*qy+qr*qz), R11 = 1.f-2.f*(qx*qx+qz*qz), R12 = 2.f*(qy*qz-qr*qx);
        float R20 = 2.f*(qx*qz-qr*qy), R21 = 2.f*(qy*qz+qr*qx), R22 = 1.f-2.f*(qx*qx+qy*qy);
        float M00=R00*sx, M01=R01*sy, M02=R02*sz;
        float M10=R10*sx, M11=R11*sy, M12=R12*sz;
        float M20=R20*sx, M21=R21*sy, M22=R22*sz;
        float S00 = M00*M00+M01*M01+M02*M02;
        float S01 = M00*M10+M01*M11+M02*M12;
        float S02 = M00*M20+M01*M21+M02*M22;
        float S11 = M10*M10+M11*M11+M12*M12;
        float S12 = M10*M20+M11*M21+M12*M22;
        float S22 = M20*M20+M21*M21+M22*M22;

        const float* V = view_mat;  // row-major 4x4
        float t0 = V[0]*mx + V[1]*my + V[2]*mz  + V[3];
        float t1 = V[4]*mx + V[5]*my + V[6]*mz  + V[7];
        float t2 = V[8]*mx + V[9]*my + V[10]*mz + V[11];
        bool valid_z = t2 > 0.2f;
        float tzs = valid_z ? t2 : 1.0f;
        float limx = 1.3f*tanx, limy = 1.3f*tany;
        float txc = fminf(fmaxf(t0/tzs, -limx), limx) * tzs;
        float tyc = fminf(fmaxf(t1/tzs, -limy), limy) * tzs;
        float inv_tz = 1.f / tzs;
        float J00 = fx*inv_tz, J02 = -fx*txc*inv_tz*inv_tz;
        float J11 = fy*inv_tz, J12 = -fy*tyc*inv_tz*inv_tz;
        float T200 = J00*V[0] + J02*V[8];
        float T201 = J00*V[1] + J02*V[9];
        float T202 = J00*V[2] + J02*V[10];
        float T210 = J11*V[4] + J12*V[8];
        float T211 = J11*V[5] + J12*V[9];
        float T212 = J11*V[6] + J12*V[10];
        float u0 = S00*T200 + S01*T201 + S02*T202;
        float u1 = S01*T200 + S11*T201 + S12*T202;
        float u2 = S02*T200 + S12*T201 + S22*T202;
        float cov00 = T200*u0 + T201*u1 + T202*u2;
        float cov01 = T210*u0 + T211*u1 + T212*u2;
        float v0 = S00*T210 + S01*T211 + S02*T212;
        float v1 = S01*T210 + S11*T211 + S12*T212;
        float v2 = S02*T210 + S12*T211 + S22*T212;
        float cov11 = T210*v0 + T211*v1 + T212*v2;
        float a = cov00 + 0.3f;
        float c = cov11 + 0.3f;
        float b = cov01;
        float det = a*c - b*b;
        bool valid = valid_z && (det > 0.f);
        float inv_det = (det > 0.f) ? (1.f/det) : 0.f;
        float Aq = c*inv_det, Bq = -b*inv_det, Cq = a*inv_det;

        const float* P = proj_mat;
        float ph0 = P[0]*mx  + P[1]*my  + P[2]*mz  + P[3];
        float ph1 = P[4]*mx  + P[5]*my  + P[6]*mz  + P[7];
        float ph3 = P[12]*mx + P[13]*my + P[14]*mz + P[15];
        float pw = 1.f / (ph3 + 1e-7f);
        float px = ((ph0*pw + 1.f)*Wf - 1.f)*0.5f;
        float py = ((ph1*pw + 1.f)*Hf - 1.f)*0.5f;

        // SH eval — coefficients via 12 coalesced float4 loads
        float dxm = mx - cam_pos[0], dym = my - cam_pos[1], dzm = mz - cam_pos[2];
        float dn = sqrtf(dxm*dxm + dym*dym + dzm*dzm);
        float X = dxm/dn, Y = dym/dn, Z = dzm/dn;
        float xx = X*X, yy = Y*Y, zz = Z*Z;
        float xy = X*Y, yz = Y*Z, xz = X*Z;
        float sc[48];
        {
            const float4* s4 = (const float4*)(shs + i*48);
            #pragma unroll
            for (int k = 0; k < 12; k++) {
                float4 v = s4[k];
                sc[4*k] = v.x; sc[4*k+1] = v.y; sc[4*k+2] = v.z; sc[4*k+3] = v.w;
            }
        }
        float col[3];
        #pragma unroll
        for (int ch = 0; ch < 3; ch++) {
            float res = 0.28209479177387814f * sc[ch];
            res += -0.4886025119029199f * Y * sc[3+ch]
                 +  0.4886025119029199f * Z * sc[6+ch]
                 -  0.4886025119029199f * X * sc[9+ch];
            res +=  1.0925484305920792f * xy * sc[12+ch]
                 + (-1.0925484305920792f) * yz * sc[15+ch]
                 +  0.31539156525252005f * (2.f*zz - xx - yy) * sc[18+ch]
                 + (-1.0925484305920792f) * xz * sc[21+ch]
                 +  0.5462742152960396f * (xx - yy) * sc[24+ch];
            res += -0.5900435899266435f * Y * (3.f*xx - yy) * sc[27+ch]
                 +  2.890611442640554f  * xy * Z * sc[30+ch]
                 + (-0.4570457994644658f) * Y * (4.f*zz - xx - yy) * sc[33+ch]
                 +  0.3731763325901154f  * Z * (2.f*zz - 3.f*xx - 3.f*yy) * sc[36+ch]
                 + (-0.4570457994644658f) * X * (4.f*zz - xx - yy) * sc[39+ch]
                 +  1.445305721320277f   * Z * (xx - yy) * sc[42+ch]
                 + (-0.5900435899266435f) * X * (xx - yy - zz) * sc[45+ch];
            col[ch] = fmaxf(res + 0.5f, 0.f);
        }

        float op = valid ? opacities[i] : 0.f;
        float dpt = valid ? t2 : 1e10f;

        // exact alpha>=1/255 ellipse extents: rx = sqrt(tau*a), tau = 2 ln(255 op)
        float tau = 2.f * logf(255.f * fmaxf(op, 1e-20f));
        bool has = valid && (op * 255.f > 1.f) && (tau > 0.f);
        float rx = has ? (sqrtf(tau * a) + 0.01f) : 0.f;
        float ry = has ? (sqrtf(tau * c) + 0.01f) : 0.f;

        // exact tile range at 8-px granularity:
        // hit(tx) <=> ceil((bx0-7)/8) <= tx <= floor(bx1/8)
        unsigned trange = 255u;                    // tx0=255 => never hits
        if (has) {
            int tx0 = (int)ceilf((px - rx - 7.f) * 0.125f);
            int tx1 = (int)floorf((px + rx) * 0.125f);
            int ty0 = (int)ceilf((py - ry - 7.f) * 0.125f);
            int ty1 = (int)floorf((py + ry) * 0.125f);
            tx0 = max(tx0, 0); ty0 = max(ty0, 0);
            tx1 = min(tx1, tilesX - 1); ty1 = min(ty1, tilesY - 1);
            if (tx0 <= tx1 && ty0 <= ty1)
                trange = (unsigned)tx0 | ((unsigned)tx1 << 8)
                       | ((unsigned)ty0 << 16) | ((unsigned)ty1 << 24);
        }
        grec[i] = make_uint4(__float_as_uint(dpt), (unsigned)i, trange, 0u);

        rec[i*3 + 0] = make_float4(px, py, -0.5f*LOG2E*Aq, -LOG2E*Bq);
        rec[i*3 + 1] = make_float4(-0.5f*LOG2E*Cq, op, col[0], col[1]);
        rec[i*3 + 2] = make_float4(col[2], 0.f, 0.f, 0.f);
    }

    // ================= grid-wide barrier (cross-XCD visibility) ===========
    cg::this_grid().sync();

    // ================= phase B: rasterize tile `blk` ======================
    int tilesX = W >> 3;
    int tx = blk % tilesX, ty = blk / tilesX;
    int lx = lane & 7, ly = lane >> 3;
    float pixx = (float)(tx*8 + lx);
    float pixy = (float)(ty*8 + ly);

    // ---- gather hit list (index-ordered), 4x unrolled packed loads
    int cnt = 0;
    const uint4 miss = make_uint4(0u, 0u, 255u, 0u);
    for (int base = 0; base < N; base += 256) {
        int g0 = base + lane;
        uint4 ra = (g0       < N) ? grec[g0]       : miss;
        uint4 rb = (g0 + 64  < N) ? grec[g0 + 64]  : miss;
        uint4 rc = (g0 + 128 < N) ? grec[g0 + 128] : miss;
        uint4 rd = (g0 + 192 < N) ? grec[g0 + 192] : miss;
        #pragma unroll
        for (int s = 0; s < 4; s++) {
            uint4 r = (s == 0) ? ra : (s == 1) ? rb : (s == 2) ? rc : rd;
            unsigned tr = r.z;
            bool hit = (tx >= (int)(tr & 255u)) & (tx <= (int)((tr >> 8) & 255u))
                     & (ty >= (int)((tr >> 16) & 255u)) & (ty <= (int)(tr >> 24));
            unsigned long long mask = __ballot(hit);
            if (hit) {
                int pos = cnt + __popcll(mask & ((1ull << lane) - 1ull));
                skey[pos] = ((unsigned long long)r.x << 32) | r.y;
            }
            cnt += __popcll(mask);
        }
    }
    __syncthreads();

    float T = 1.f, Cr = 0.f, Cg = 0.f, Cb = 0.f;
    if (cnt > 0 && cnt <= 64) {
        // ---- in-register shfl sort; own key = sorted list entry
        unsigned long long key = (lane < cnt) ? skey[lane] : ~0ull;
        for (int k = 2; k <= 64; k <<= 1)
            for (int j = k >> 1; j >= 1; j >>= 1)
                key = bstage_shfl(key, lane, j, k);
        int gg = (lane < cnt) ? (int)(unsigned)key : 0;
        float4 r0 = rec[gg*3 + 0];
        float4 r1 = rec[gg*3 + 1];
        float4 r2 = rec[gg*3 + 2];
        for (int m = 0; m < cnt; m++) {
            float gpx = rlane(r0.x, m), gpy = rlane(r0.y, m);
            float gA  = rlane(r0.z, m), gB  = rlane(r0.w, m);
            float gC  = rlane(r1.x, m), gop = rlane(r1.y, m);
            float gcr = rlane(r1.z, m), gcg = rlane(r1.w, m);
            float gcb = rlane(r2.x, m);
            float dx = gpx - pixx, dy = gpy - pixy;
            float p2 = fmaf(gA, dx*dx, fmaf(gC, dy*dy, gB*(dx*dy)));
            float e  = __builtin_amdgcn_exp2f(p2);     // power<=0 guaranteed
            float alpha = fminf(gop * e, 0.99f);
            float a2 = (alpha >= (1.f/255.f)) ? alpha : 0.f;
            float w = a2 * T;
            Cr = fmaf(gcr, w, Cr);
            Cg = fmaf(gcg, w, Cg);
            Cb = fmaf(gcb, w, Cb);
            T  = T - a2 * T;
            if ((m & 15) == 15 && __all(T < 1e-4f)) break;
        }
    } else if (cnt > 64) {
        // ---- LDS bitonic sort then chunked blend
        int P = 128;
        while (P < cnt) P <<= 1;
        for (int i2 = cnt + lane; i2 < P; i2 += 64) skey[i2] = ~0ull;
        __syncthreads();
        for (int k = 2; k <= P; k <<= 1) {
            for (int j = k >> 1; j >= 1; j >>= 1) {
                for (int i2 = lane; i2 < P; i2 += 64) {
                    int ixj = i2 ^ j;
                    if (ixj > i2) {
                        bool asc = (i2 & k) == 0;
                        unsigned long long u = skey[i2], v = skey[ixj];
                        if ((u > v) == asc) { skey[i2] = v; skey[ixj] = u; }
                    }
                }
                __syncthreads();
            }
        }
        bool dead = false;
        for (int c = 0; c < cnt && !dead; c += 64) {
            int len = min(64, cnt - c);
            int idx = c + lane;
            int gg = (idx < cnt) ? (int)(unsigned)skey[idx] : 0;
            float4 r0 = rec[gg*3 + 0];
            float4 r1 = rec[gg*3 + 1];
            float4 r2 = rec[gg*3 + 2];
            for (int m = 0; m < len; m++) {
                float gpx = rlane(r0.x, m), gpy = rlane(r0.y, m);
                float gA  = rlane(r0.z, m), gB  = rlane(r0.w, m);
                float gC  = rlane(r1.x, m), gop = rlane(r1.y, m);
                float gcr = rlane(r1.z, m), gcg = rlane(r1.w, m);
                float gcb = rlane(r2.x, m);
                float dx = gpx - pixx, dy = gpy - pixy;
                float p2 = fmaf(gA, dx*dx, fmaf(gC, dy*dy, gB*(dx*dy)));
                float e  = __builtin_amdgcn_exp2f(p2);
                float alpha = fminf(gop * e, 0.99f);
                float a2 = (alpha >= (1.f/255.f)) ? alpha : 0.f;
                float w = a2 * T;
                Cr = fmaf(gcr, w, Cr);
                Cg = fmaf(gcg, w, Cg);
                Cb = fmaf(gcb, w, Cb);
                T  = T - a2 * T;
                if ((m & 15) == 15 && __all(T < 1e-4f)) { dead = true; break; }
            }
            if (__all(T < 1e-4f)) dead = true;
        }
    }

    int p = (ty*8 + ly) * W + tx*8 + lx;
    out[p]        = Cr + background[0]*T;
    out[HW + p]   = Cg + background[1]*T;
    out[2*HW + p] = Cb + background[2]*T;
}

// ---------------------------------------------------------------- launcher
extern "C" void kernel_launch(void* const* d_in, const int* in_sizes, int n_in,
                              void* d_out, int out_size, void* d_ws, size_t ws_size,
                              hipStream_t stream) {
    const float* background = (const float*)d_in[0];
    const float* means3D    = (const float*)d_in[1];
    const float* opacities  = (const float*)d_in[2];
    const float* scales     = (const float*)d_in[3];
    const float* rotations  = (const float*)d_in[4];
    const float* shs        = (const float*)d_in[5];
    const float* view_mat   = (const float*)d_in[6];
    const float* proj_mat   = (const float*)d_in[7];
    const float* cam_pos    = (const float*)d_in[8];
    const float* tanx       = (const float*)d_in[9];
    const float* tany       = (const float*)d_in[10];
    const int*   hp         = (const int*)d_in[11];
    const int*   wp         = (const int*)d_in[12];

    int N  = in_sizes[2];        // opacities: (N,1)
    int HW = out_size / 3;
    int W  = 256;                // fixed per problem (H*W == HW)
    int H  = HW / W;
    float* out = (float*)d_out;

    uint4*  grec = (uint4*)d_ws;                 // NG uint4
    float4* rec  = (float4*)(grec + NG);         // NG*3 float4

    int tiles = (W >> 3) * (H >> 3);             // 1024 blocks (>= 16 prep blocks)

    void* args[] = {
        (void*)&means3D, (void*)&opacities, (void*)&scales, (void*)&rotations,
        (void*)&shs, (void*)&view_mat, (void*)&proj_mat, (void*)&cam_pos,
        (void*)&tanx, (void*)&tany, (void*)&hp, (void*)&wp,
        (void*)&grec, (void*)&rec, (void*)&background, (void*)&out,
        (void*)&N, (void*)&W, (void*)&HW
    };
    hipLaunchCooperativeKernel((void*)fused_kernel, dim3(tiles), dim3(64),
                               args, 0, stream);
}

// Round 9
// 47.001 us; speedup vs baseline: 1.6989x; 1.6989x over previous
//
#include <hip/hip_runtime.h>
#include <math.h>

#define NG 1024          // N_GAUSS (power of two)
#define NPREPB 16        // prep blocks (NG/64)
#define MAGIC 0x13579BDFu
#define LOG2E 1.4426950408889634f

// grec[i]  = {depth_bits, idx, tile_range(tx0|tx1<<8|ty0<<16|ty1<<24), 0}
// rec[i*3] = r0=(px,py,A2,B2) r1=(C2,op,cr,cg) r2=(cb,0,0,0)
// power_log2 = A2*dx^2 + C2*dy^2 + B2*dx*dy   (A2 = -0.5*log2e*A, etc.)

__device__ inline unsigned long long bstage_shfl(unsigned long long key,
                                                 int tid, int j, int k) {
    unsigned long long partner = __shfl_xor(key, j, 64);
    bool lower = (tid & j) == 0;
    bool asc   = (tid & k) == 0;
    return ((key < partner) == (lower == asc)) ? key : partner;
}

__device__ inline float rlane(float v, int l) {
    return __int_as_float(__builtin_amdgcn_readlane(__float_as_int(v), l));
}

// Single cooperative kernel. Blocks 0..15 prep 64 gaussians each, then
// release-store a MAGIC flag (16 producers). All blocks acquire-poll the 16
// flags (read-only, lane-parallel) and then rasterize their 8x8 tile.
// NOT cg::grid.sync(): that is 1024 serialized system-scope RMW arrivals
// (~50us measured r8); this is 16 stores + broadcastable loads.
__global__ void __launch_bounds__(64) fused_kernel(
    const float* __restrict__ means3D, const float* __restrict__ opacities,
    const float* __restrict__ scales,  const float* __restrict__ rotations,
    const float* __restrict__ shs,     const float* __restrict__ view_mat,
    const float* __restrict__ proj_mat,const float* __restrict__ cam_pos,
    const float* __restrict__ tanx_p,  const float* __restrict__ tany_p,
    const int* __restrict__ h_p,       const int* __restrict__ w_p,
    uint4* __restrict__ grec, float4* __restrict__ rec,
    unsigned* __restrict__ flags,
    const float* __restrict__ background, float* __restrict__ out,
    int N, int W, int HW)
{
    __shared__ unsigned long long skey[NG];
    int blk  = blockIdx.x;
    int lane = threadIdx.x;

    // ================= phase A: preprocess (blocks 0..15) =================
    if (blk < NPREPB) {
        int i = blk * 64 + lane;
        if (i < N) {
            float tanx = tanx_p[0], tany = tany_p[0];
            float Wf = (float)w_p[0], Hf = (float)h_p[0];
            int tilesX = w_p[0] >> 3, tilesY = h_p[0] >> 3;
            float fx = Wf / (2.f * tanx), fy = Hf / (2.f * tany);

            float mx = means3D[3*i], my = means3D[3*i+1], mz = means3D[3*i+2];

            float4 q4 = ((const float4*)rotations)[i];
            float qr = q4.x, qx = q4.y, qy = q4.z, qz = q4.w;
            float qn = sqrtf(qr*qr + qx*qx + qy*qy + qz*qz);
            qr /= qn; qx /= qn; qy /= qn; qz /= qn;
            float sx = scales[3*i], sy = scales[3*i+1], sz = scales[3*i+2];
            float R00 = 1.f-2.f*(qy*qy+qz*qz), R01 = 2.f*(qx*qy-qr*qz), R02 = 2.f*(qx*qz+qr*qy);
            float R10 = 2.f*(qx*qy+qr*qz), R11 = 1.f-2.f*(qx*qx+qz*qz), R12 = 2.f*(qy*qz-qr*qx);
            float R20 = 2.f*(qx*qz-qr*qy), R21 = 2.f*(qy*qz+qr*qx), R22 = 1.f-2.f*(qx*qx+qy*qy);
            float M00=R00*sx, M01=R01*sy, M02=R02*sz;
            float M10=R10*sx, M11=R11*sy, M12=R12*sz;
            float M20=R20*sx, M21=R21*sy, M22=R22*sz;
            float S00 = M00*M00+M01*M01+M02*M02;
            float S01 = M00*M10+M01*M11+M02*M12;
            float S02 = M00*M20+M01*M21+M02*M22;
            float S11 = M10*M10+M11*M11+M12*M12;
            float S12 = M10*M20+M11*M21+M12*M22;
            float S22 = M20*M20+M21*M21+M22*M22;

            const float* V = view_mat;  // row-major 4x4
            float t0 = V[0]*mx + V[1]*my + V[2]*mz  + V[3];
            float t1 = V[4]*mx + V[5]*my + V[6]*mz  + V[7];
            float t2 = V[8]*mx + V[9]*my + V[10]*mz + V[11];
            bool valid_z = t2 > 0.2f;
            float tzs = valid_z ? t2 : 1.0f;
            float limx = 1.3f*tanx, limy = 1.3f*tany;
            float txc = fminf(fmaxf(t0/tzs, -limx), limx) * tzs;
            float tyc = fminf(fmaxf(t1/tzs, -limy), limy) * tzs;
            float inv_tz = 1.f / tzs;
            float J00 = fx*inv_tz, J02 = -fx*txc*inv_tz*inv_tz;
            float J11 = fy*inv_tz, J12 = -fy*tyc*inv_tz*inv_tz;
            float T200 = J00*V[0] + J02*V[8];
            float T201 = J00*V[1] + J02*V[9];
            float T202 = J00*V[2] + J02*V[10];
            float T210 = J11*V[4] + J12*V[8];
            float T211 = J11*V[5] + J12*V[9];
            float T212 = J11*V[6] + J12*V[10];
            float u0 = S00*T200 + S01*T201 + S02*T202;
            float u1 = S01*T200 + S11*T201 + S12*T202;
            float u2 = S02*T200 + S12*T201 + S22*T202;
            float cov00 = T200*u0 + T201*u1 + T202*u2;
            float cov01 = T210*u0 + T211*u1 + T212*u2;
            float v0 = S00*T210 + S01*T211 + S02*T212;
            float v1 = S01*T210 + S11*T211 + S12*T212;
            float v2 = S02*T210 + S12*T211 + S22*T212;
            float cov11 = T210*v0 + T211*v1 + T212*v2;
            float a = cov00 + 0.3f;
            float c = cov11 + 0.3f;
            float b = cov01;
            float det = a*c - b*b;
            bool valid = valid_z && (det > 0.f);
            float inv_det = (det > 0.f) ? (1.f/det) : 0.f;
            float Aq = c*inv_det, Bq = -b*inv_det, Cq = a*inv_det;

            const float* P = proj_mat;
            float ph0 = P[0]*mx  + P[1]*my  + P[2]*mz  + P[3];
            float ph1 = P[4]*mx  + P[5]*my  + P[6]*mz  + P[7];
            float ph3 = P[12]*mx + P[13]*my + P[14]*mz + P[15];
            float pw = 1.f / (ph3 + 1e-7f);
            float px = ((ph0*pw + 1.f)*Wf - 1.f)*0.5f;
            float py = ((ph1*pw + 1.f)*Hf - 1.f)*0.5f;

            // SH eval — coefficients via 12 coalesced float4 loads
            float dxm = mx - cam_pos[0], dym = my - cam_pos[1], dzm = mz - cam_pos[2];
            float dn = sqrtf(dxm*dxm + dym*dym + dzm*dzm);
            float X = dxm/dn, Y = dym/dn, Z = dzm/dn;
            float xx = X*X, yy = Y*Y, zz = Z*Z;
            float xy = X*Y, yz = Y*Z, xz = X*Z;
            float sc[48];
            {
                const float4* s4 = (const float4*)(shs + i*48);
                #pragma unroll
                for (int k = 0; k < 12; k++) {
                    float4 v = s4[k];
                    sc[4*k] = v.x; sc[4*k+1] = v.y; sc[4*k+2] = v.z; sc[4*k+3] = v.w;
                }
            }
            float col[3];
            #pragma unroll
            for (int ch = 0; ch < 3; ch++) {
                float res = 0.28209479177387814f * sc[ch];
                res += -0.4886025119029199f * Y * sc[3+ch]
                     +  0.4886025119029199f * Z * sc[6+ch]
                     -  0.4886025119029199f * X * sc[9+ch];
                res +=  1.0925484305920792f * xy * sc[12+ch]
                     + (-1.0925484305920792f) * yz * sc[15+ch]
                     +  0.31539156525252005f * (2.f*zz - xx - yy) * sc[18+ch]
                     + (-1.0925484305920792f) * xz * sc[21+ch]
                     +  0.5462742152960396f * (xx - yy) * sc[24+ch];
                res += -0.5900435899266435f * Y * (3.f*xx - yy) * sc[27+ch]
                     +  2.890611442640554f  * xy * Z * sc[30+ch]
                     + (-0.4570457994644658f) * Y * (4.f*zz - xx - yy) * sc[33+ch]
                     +  0.3731763325901154f  * Z * (2.f*zz - 3.f*xx - 3.f*yy) * sc[36+ch]
                     + (-0.4570457994644658f) * X * (4.f*zz - xx - yy) * sc[39+ch]
                     +  1.445305721320277f   * Z * (xx - yy) * sc[42+ch]
                     + (-0.5900435899266435f) * X * (xx - yy - zz) * sc[45+ch];
                col[ch] = fmaxf(res + 0.5f, 0.f);
            }

            float op = valid ? opacities[i] : 0.f;
            float dpt = valid ? t2 : 1e10f;

            float tau = 2.f * logf(255.f * fmaxf(op, 1e-20f));
            bool has = valid && (op * 255.f > 1.f) && (tau > 0.f);
            float rx = has ? (sqrtf(tau * a) + 0.01f) : 0.f;
            float ry = has ? (sqrtf(tau * c) + 0.01f) : 0.f;

            // exact tile range at 8-px granularity
            unsigned trange = 255u;                // tx0=255 => never hits
            if (has) {
                int tx0 = (int)ceilf((px - rx - 7.f) * 0.125f);
                int tx1 = (int)floorf((px + rx) * 0.125f);
                int ty0 = (int)ceilf((py - ry - 7.f) * 0.125f);
                int ty1 = (int)floorf((py + ry) * 0.125f);
                tx0 = max(tx0, 0); ty0 = max(ty0, 0);
                tx1 = min(tx1, tilesX - 1); ty1 = min(ty1, tilesY - 1);
                if (tx0 <= tx1 && ty0 <= ty1)
                    trange = (unsigned)tx0 | ((unsigned)tx1 << 8)
                           | ((unsigned)ty0 << 16) | ((unsigned)ty1 << 24);
            }
            grec[i] = make_uint4(__float_as_uint(dpt), (unsigned)i, trange, 0u);

            rec[i*3 + 0] = make_float4(px, py, -0.5f*LOG2E*Aq, -LOG2E*Bq);
            rec[i*3 + 1] = make_float4(-0.5f*LOG2E*Cq, op, col[0], col[1]);
            rec[i*3 + 2] = make_float4(col[2], 0.f, 0.f, 0.f);
        }
        __syncthreads();   // single wave: drains this wave's stores
        if (lane == 0)
            __hip_atomic_store(&flags[blk], MAGIC,
                               __ATOMIC_RELEASE, __HIP_MEMORY_SCOPE_AGENT);
    }

    // ====== lightweight barrier: poll the 16 producer flags ======
    for (;;) {
        unsigned f = (lane < NPREPB)
            ? __hip_atomic_load(&flags[lane],
                                __ATOMIC_ACQUIRE, __HIP_MEMORY_SCOPE_AGENT)
            : MAGIC;
        if (__all(f == MAGIC)) break;
        __builtin_amdgcn_s_sleep(8);
    }

    // ================= phase B: rasterize tile `blk` ======================
    int tilesX = W >> 3;
    int tx = blk % tilesX, ty = blk / tilesX;
    int lx = lane & 7, ly = lane >> 3;
    float pixx = (float)(tx*8 + lx);
    float pixy = (float)(ty*8 + ly);

    // ---- gather hit list (index-ordered), 4x unrolled packed loads
    int cnt = 0;
    const uint4 miss = make_uint4(0u, 0u, 255u, 0u);
    for (int base = 0; base < N; base += 256) {
        int g0 = base + lane;
        uint4 ra = (g0       < N) ? grec[g0]       : miss;
        uint4 rb = (g0 + 64  < N) ? grec[g0 + 64]  : miss;
        uint4 rc = (g0 + 128 < N) ? grec[g0 + 128] : miss;
        uint4 rd = (g0 + 192 < N) ? grec[g0 + 192] : miss;
        #pragma unroll
        for (int s = 0; s < 4; s++) {
            uint4 r = (s == 0) ? ra : (s == 1) ? rb : (s == 2) ? rc : rd;
            unsigned tr = r.z;
            bool hit = (tx >= (int)(tr & 255u)) & (tx <= (int)((tr >> 8) & 255u))
                     & (ty >= (int)((tr >> 16) & 255u)) & (ty <= (int)(tr >> 24));
            unsigned long long mask = __ballot(hit);
            if (hit) {
                int pos = cnt + __popcll(mask & ((1ull << lane) - 1ull));
                skey[pos] = ((unsigned long long)r.x << 32) | r.y;
            }
            cnt += __popcll(mask);
        }
    }
    __syncthreads();

    float T = 1.f, Cr = 0.f, Cg = 0.f, Cb = 0.f;
    if (cnt > 0 && cnt <= 64) {
        // ---- in-register shfl sort; own key = sorted list entry
        unsigned long long key = (lane < cnt) ? skey[lane] : ~0ull;
        for (int k = 2; k <= 64; k <<= 1)
            for (int j = k >> 1; j >= 1; j >>= 1)
                key = bstage_shfl(key, lane, j, k);
        int gg = (lane < cnt) ? (int)(unsigned)key : 0;
        float4 r0 = rec[gg*3 + 0];
        float4 r1 = rec[gg*3 + 1];
        float4 r2 = rec[gg*3 + 2];
        for (int m = 0; m < cnt; m++) {
            float gpx = rlane(r0.x, m), gpy = rlane(r0.y, m);
            float gA  = rlane(r0.z, m), gB  = rlane(r0.w, m);
            float gC  = rlane(r1.x, m), gop = rlane(r1.y, m);
            float gcr = rlane(r1.z, m), gcg = rlane(r1.w, m);
            float gcb = rlane(r2.x, m);
            float dx = gpx - pixx, dy = gpy - pixy;
            float p2 = fmaf(gA, dx*dx, fmaf(gC, dy*dy, gB*(dx*dy)));
            float e  = __builtin_amdgcn_exp2f(p2);     // power<=0 guaranteed
            float alpha = fminf(gop * e, 0.99f);
            float a2 = (alpha >= (1.f/255.f)) ? alpha : 0.f;
            float w = a2 * T;
            Cr = fmaf(gcr, w, Cr);
            Cg = fmaf(gcg, w, Cg);
            Cb = fmaf(gcb, w, Cb);
            T  = T - a2 * T;
            if ((m & 15) == 15 && __all(T < 1e-4f)) break;
        }
    } else if (cnt > 64) {
        // ---- LDS bitonic sort then chunked blend
        int P = 128;
        while (P < cnt) P <<= 1;
        for (int i2 = cnt + lane; i2 < P; i2 += 64) skey[i2] = ~0ull;
        __syncthreads();
        for (int k = 2; k <= P; k <<= 1) {
            for (int j = k >> 1; j >= 1; j >>= 1) {
                for (int i2 = lane; i2 < P; i2 += 64) {
                    int ixj = i2 ^ j;
                    if (ixj > i2) {
                        bool asc = (i2 & k) == 0;
                        unsigned long long u = skey[i2], v = skey[ixj];
                        if ((u > v) == asc) { skey[i2] = v; skey[ixj] = u; }
                    }
                }
                __syncthreads();
            }
        }
        bool dead = false;
        for (int c = 0; c < cnt && !dead; c += 64) {
            int len = min(64, cnt - c);
            int idx = c + lane;
            int gg = (idx < cnt) ? (int)(unsigned)skey[idx] : 0;
            float4 r0 = rec[gg*3 + 0];
            float4 r1 = rec[gg*3 + 1];
            float4 r2 = rec[gg*3 + 2];
            for (int m = 0; m < len; m++) {
                float gpx = rlane(r0.x, m), gpy = rlane(r0.y, m);
                float gA  = rlane(r0.z, m), gB  = rlane(r0.w, m);
                float gC  = rlane(r1.x, m), gop = rlane(r1.y, m);
                float gcr = rlane(r1.z, m), gcg = rlane(r1.w, m);
                float gcb = rlane(r2.x, m);
                float dx = gpx - pixx, dy = gpy - pixy;
                float p2 = fmaf(gA, dx*dx, fmaf(gC, dy*dy, gB*(dx*dy)));
                float e  = __builtin_amdgcn_exp2f(p2);
                float alpha = fminf(gop * e, 0.99f);
                float a2 = (alpha >= (1.f/255.f)) ? alpha : 0.f;
                float w = a2 * T;
                Cr = fmaf(gcr, w, Cr);
                Cg = fmaf(gcg, w, Cg);
                Cb = fmaf(gcb, w, Cb);
                T  = T - a2 * T;
                if ((m & 15) == 15 && __all(T < 1e-4f)) { dead = true; break; }
            }
            if (__all(T < 1e-4f)) dead = true;
        }
    }

    int p = (ty*8 + ly) * W + tx*8 + lx;
    out[p]        = Cr + background[0]*T;
    out[HW + p]   = Cg + background[1]*T;
    out[2*HW + p] = Cb + background[2]*T;
}

// ---------------------------------------------------------------- launcher
extern "C" void kernel_launch(void* const* d_in, const int* in_sizes, int n_in,
                              void* d_out, int out_size, void* d_ws, size_t ws_size,
                              hipStream_t stream) {
    const float* background = (const float*)d_in[0];
    const float* means3D    = (const float*)d_in[1];
    const float* opacities  = (const float*)d_in[2];
    const float* scales     = (const float*)d_in[3];
    const float* rotations  = (const float*)d_in[4];
    const float* shs        = (const float*)d_in[5];
    const float* view_mat   = (const float*)d_in[6];
    const float* proj_mat   = (const float*)d_in[7];
    const float* cam_pos    = (const float*)d_in[8];
    const float* tanx       = (const float*)d_in[9];
    const float* tany       = (const float*)d_in[10];
    const int*   hp         = (const int*)d_in[11];
    const int*   wp         = (const int*)d_in[12];

    int N  = in_sizes[2];        // opacities: (N,1)
    int HW = out_size / 3;
    int W  = 256;                // fixed per problem (H*W == HW)
    int H  = HW / W;
    float* out = (float*)d_out;

    uint4*    grec  = (uint4*)d_ws;                  // NG uint4   (16 KB)
    float4*   rec   = (float4*)(grec + NG);          // NG*3 float4 (48 KB)
    unsigned* flags = (unsigned*)(rec + NG*3);       // NPREPB u32

    int tiles = (W >> 3) * (H >> 3);                 // 1024 blocks

    void* args[] = {
        (void*)&means3D, (void*)&opacities, (void*)&scales, (void*)&rotations,
        (void*)&shs, (void*)&view_mat, (void*)&proj_mat, (void*)&cam_pos,
        (void*)&tanx, (void*)&tany, (void*)&hp, (void*)&wp,
        (void*)&grec, (void*)&rec, (void*)&flags, (void*)&background,
        (void*)&out, (void*)&N, (void*)&W, (void*)&HW
    };
    hipLaunchCooperativeKernel((void*)fused_kernel, dim3(tiles), dim3(64),
                               args, 0, stream);
}

// Round 10
// 18.283 us; speedup vs baseline: 4.3674x; 2.5707x over previous
//
#include <hip/hip_runtime.h>
#include <math.h>

#define NG 1024          // N_GAUSS (power of two)
#define LOG2E 1.4426950408889634f

// grec[i] (u64) = depth_bits[63:32] | idx[29:20] | tx0[4:0] tx1[9:5] ty0[14:10] ty1[19:15]
//   - sorting by the full u64 sorts by (depth, idx, trange) == stable depth argsort
//   - miss encoding: tx0=31, tx1=0  (no tile satisfies tx0<=tx<=tx1)
// rec[i*3] = r0=(px,py,A2,B2) r1=(C2,op,cr,cg) r2=(cb,0,0,0)
// power_log2 = A2*dx^2 + C2*dy^2 + B2*dx*dy   (A2 = -0.5*log2e*A, etc.)

// ---------------------------------------------------------------- preprocess
__global__ void prep_kernel(
    const float* __restrict__ means3D, const float* __restrict__ opacities,
    const float* __restrict__ scales,  const float* __restrict__ rotations,
    const float* __restrict__ shs,     const float* __restrict__ view_mat,
    const float* __restrict__ proj_mat,const float* __restrict__ cam_pos,
    const float* __restrict__ tanx_p,  const float* __restrict__ tany_p,
    const int* __restrict__ h_p,       const int* __restrict__ w_p,
    unsigned long long* __restrict__ grec, float4* __restrict__ rec, int N)
{
    int i = blockIdx.x * blockDim.x + threadIdx.x;
    if (i >= N) return;
    float tanx = tanx_p[0], tany = tany_p[0];
    float Wf = (float)w_p[0], Hf = (float)h_p[0];
    int tilesX = w_p[0] >> 3, tilesY = h_p[0] >> 3;
    float fx = Wf / (2.f * tanx), fy = Hf / (2.f * tany);

    float mx = means3D[3*i], my = means3D[3*i+1], mz = means3D[3*i+2];

    float4 q4 = ((const float4*)rotations)[i];
    float qr = q4.x, qx = q4.y, qy = q4.z, qz = q4.w;
    float qn = sqrtf(qr*qr + qx*qx + qy*qy + qz*qz);
    qr /= qn; qx /= qn; qy /= qn; qz /= qn;
    float sx = scales[3*i], sy = scales[3*i+1], sz = scales[3*i+2];
    float R00 = 1.f-2.f*(qy*qy+qz*qz), R01 = 2.f*(qx*qy-qr*qz), R02 = 2.f*(qx*qz+qr*qy);
    float R10 = 2.f*(qx*qy+qr*qz), R11 = 1.f-2.f*(qx*qx+qz*qz), R12 = 2.f*(qy*qz-qr*qx);
    float R20 = 2.f*(qx*qz-qr*qy), R21 = 2.f*(qy*qz+qr*qx), R22 = 1.f-2.f*(qx*qx+qy*qy);
    float M00=R00*sx, M01=R01*sy, M02=R02*sz;
    float M10=R10*sx, M11=R11*sy, M12=R12*sz;
    float M20=R20*sx, M21=R21*sy, M22=R22*sz;
    float S00 = M00*M00+M01*M01+M02*M02;
    float S01 = M00*M10+M01*M11+M02*M12;
    float S02 = M00*M20+M01*M21+M02*M22;
    float S11 = M10*M10+M11*M11+M12*M12;
    float S12 = M10*M20+M11*M21+M12*M22;
    float S22 = M20*M20+M21*M21+M22*M22;

    const float* V = view_mat;  // row-major 4x4
    float t0 = V[0]*mx + V[1]*my + V[2]*mz  + V[3];
    float t1 = V[4]*mx + V[5]*my + V[6]*mz  + V[7];
    float t2 = V[8]*mx + V[9]*my + V[10]*mz + V[11];
    bool valid_z = t2 > 0.2f;
    float tzs = valid_z ? t2 : 1.0f;
    float limx = 1.3f*tanx, limy = 1.3f*tany;
    float txc = fminf(fmaxf(t0/tzs, -limx), limx) * tzs;
    float tyc = fminf(fmaxf(t1/tzs, -limy), limy) * tzs;
    float inv_tz = 1.f / tzs;
    float J00 = fx*inv_tz, J02 = -fx*txc*inv_tz*inv_tz;
    float J11 = fy*inv_tz, J12 = -fy*tyc*inv_tz*inv_tz;
    float T200 = J00*V[0] + J02*V[8];
    float T201 = J00*V[1] + J02*V[9];
    float T202 = J00*V[2] + J02*V[10];
    float T210 = J11*V[4] + J12*V[8];
    float T211 = J11*V[5] + J12*V[9];
    float T212 = J11*V[6] + J12*V[10];
    float u0 = S00*T200 + S01*T201 + S02*T202;
    float u1 = S01*T200 + S11*T201 + S12*T202;
    float u2 = S02*T200 + S12*T201 + S22*T202;
    float cov00 = T200*u0 + T201*u1 + T202*u2;
    float cov01 = T210*u0 + T211*u1 + T212*u2;
    float v0 = S00*T210 + S01*T211 + S02*T212;
    float v1 = S01*T210 + S11*T211 + S12*T212;
    float v2 = S02*T210 + S12*T211 + S22*T212;
    float cov11 = T210*v0 + T211*v1 + T212*v2;
    float a = cov00 + 0.3f;
    float c = cov11 + 0.3f;
    float b = cov01;
    float det = a*c - b*b;
    bool valid = valid_z && (det > 0.f);
    float inv_det = (det > 0.f) ? (1.f/det) : 0.f;
    float Aq = c*inv_det, Bq = -b*inv_det, Cq = a*inv_det;

    const float* P = proj_mat;
    float ph0 = P[0]*mx  + P[1]*my  + P[2]*mz  + P[3];
    float ph1 = P[4]*mx  + P[5]*my  + P[6]*mz  + P[7];
    float ph3 = P[12]*mx + P[13]*my + P[14]*mz + P[15];
    float pw = 1.f / (ph3 + 1e-7f);
    float px = ((ph0*pw + 1.f)*Wf - 1.f)*0.5f;
    float py = ((ph1*pw + 1.f)*Hf - 1.f)*0.5f;

    // SH eval — coefficients via 12 coalesced float4 loads
    float dxm = mx - cam_pos[0], dym = my - cam_pos[1], dzm = mz - cam_pos[2];
    float dn = sqrtf(dxm*dxm + dym*dym + dzm*dzm);
    float X = dxm/dn, Y = dym/dn, Z = dzm/dn;
    float xx = X*X, yy = Y*Y, zz = Z*Z;
    float xy = X*Y, yz = Y*Z, xz = X*Z;
    float sc[48];
    {
        const float4* s4 = (const float4*)(shs + i*48);
        #pragma unroll
        for (int k = 0; k < 12; k++) {
            float4 v = s4[k];
            sc[4*k] = v.x; sc[4*k+1] = v.y; sc[4*k+2] = v.z; sc[4*k+3] = v.w;
        }
    }
    float col[3];
    #pragma unroll
    for (int ch = 0; ch < 3; ch++) {
        float res = 0.28209479177387814f * sc[ch];
        res += -0.4886025119029199f * Y * sc[3+ch]
             +  0.4886025119029199f * Z * sc[6+ch]
             -  0.4886025119029199f * X * sc[9+ch];
        res +=  1.0925484305920792f * xy * sc[12+ch]
             + (-1.0925484305920792f) * yz * sc[15+ch]
             +  0.31539156525252005f * (2.f*zz - xx - yy) * sc[18+ch]
             + (-1.0925484305920792f) * xz * sc[21+ch]
             +  0.5462742152960396f * (xx - yy) * sc[24+ch];
        res += -0.5900435899266435f * Y * (3.f*xx - yy) * sc[27+ch]
             +  2.890611442640554f  * xy * Z * sc[30+ch]
             + (-0.4570457994644658f) * Y * (4.f*zz - xx - yy) * sc[33+ch]
             +  0.3731763325901154f  * Z * (2.f*zz - 3.f*xx - 3.f*yy) * sc[36+ch]
             + (-0.4570457994644658f) * X * (4.f*zz - xx - yy) * sc[39+ch]
             +  1.445305721320277f   * Z * (xx - yy) * sc[42+ch]
             + (-0.5900435899266435f) * X * (xx - yy - zz) * sc[45+ch];
        col[ch] = fmaxf(res + 0.5f, 0.f);
    }

    float op = valid ? opacities[i] : 0.f;
    float dpt = valid ? t2 : 1e10f;

    // exact alpha>=1/255 ellipse extents: rx = sqrt(tau*a), tau = 2 ln(255 op)
    float tau = 2.f * logf(255.f * fmaxf(op, 1e-20f));
    bool has = valid && (op * 255.f > 1.f) && (tau > 0.f);
    float rx = has ? (sqrtf(tau * a) + 0.01f) : 0.f;
    float ry = has ? (sqrtf(tau * c) + 0.01f) : 0.f;

    // exact tile range at 8-px granularity:
    // hit(tx) <=> ceil((bx0-7)/8) <= tx <= floor(bx1/8)
    unsigned trange = 31u;                 // tx0=31, tx1=0 => never hits
    if (has) {
        int tx0 = (int)ceilf((px - rx - 7.f) * 0.125f);
        int tx1 = (int)floorf((px + rx) * 0.125f);
        int ty0 = (int)ceilf((py - ry - 7.f) * 0.125f);
        int ty1 = (int)floorf((py + ry) * 0.125f);
        tx0 = max(tx0, 0); ty0 = max(ty0, 0);
        tx1 = min(tx1, tilesX - 1); ty1 = min(ty1, tilesY - 1);
        if (tx0 <= tx1 && ty0 <= ty1)
            trange = (unsigned)tx0 | ((unsigned)tx1 << 5)
                   | ((unsigned)ty0 << 10) | ((unsigned)ty1 << 15);
    }
    grec[i] = ((unsigned long long)__float_as_uint(dpt) << 32)
            | ((unsigned long long)(unsigned)i << 20) | trange;

    rec[i*3 + 0] = make_float4(px, py, -0.5f*LOG2E*Aq, -LOG2E*Bq);
    rec[i*3 + 1] = make_float4(-0.5f*LOG2E*Cq, op, col[0], col[1]);
    rec[i*3 + 2] = make_float4(col[2], 0.f, 0.f, 0.f);
}

// --------------------------------------------------------------- rasterize
__device__ inline unsigned long long bstage_shfl(unsigned long long key,
                                                 int tid, int j, int k) {
    unsigned long long partner = __shfl_xor(key, j, 64);
    bool lower = (tid & j) == 0;
    bool asc   = (tid & k) == 0;
    return ((key < partner) == (lower == asc)) ? key : partner;
}

__device__ inline float rlane(float v, int l) {
    return __int_as_float(__builtin_amdgcn_readlane(__float_as_int(v), l));
}

// One wave per 8x8 tile. Gather via packed 8B records (4 chunks in flight),
// in-register shfl sort for cnt<=64 (no LDS round-trip), lane-parallel
// record load + readlane-broadcast blend (no memory in the blend chain).
__global__ void __launch_bounds__(64) render_kernel(
    const unsigned long long* __restrict__ grec,
    const float4* __restrict__ rec,
    const float* __restrict__ background,
    float* __restrict__ out,
    int N, int W, int HW)
{
    __shared__ unsigned long long skey[NG];
    int tile = blockIdx.x;
    int tilesX = W >> 3;
    int tx = tile % tilesX, ty = tile / tilesX;
    int lane = threadIdx.x;
    int lx = lane & 7, ly = lane >> 3;
    float pixx = (float)(tx*8 + lx);
    float pixy = (float)(ty*8 + ly);

    // ---- gather hit list (key-ordered), 4 chunks' loads in flight
    int cnt = 0;
    const unsigned long long missk = 31ull;   // tx0=31,tx1=0 -> never hits
    for (int base = 0; base < N; base += 256) {
        int g0 = base + lane;
        unsigned long long ka = (g0       < N) ? grec[g0]       : missk;
        unsigned long long kb = (g0 + 64  < N) ? grec[g0 + 64]  : missk;
        unsigned long long kc = (g0 + 128 < N) ? grec[g0 + 128] : missk;
        unsigned long long kd = (g0 + 192 < N) ? grec[g0 + 192] : missk;
        #pragma unroll
        for (int s = 0; s < 4; s++) {
            unsigned long long k = (s == 0) ? ka : (s == 1) ? kb : (s == 2) ? kc : kd;
            unsigned tr = (unsigned)k;
            bool hit = (tx >= (int)(tr & 31u)) & (tx <= (int)((tr >> 5) & 31u))
                     & (ty >= (int)((tr >> 10) & 31u)) & (ty <= (int)((tr >> 15) & 31u));
            unsigned long long mask = __ballot(hit);
            if (hit) {
                int pos = cnt + __popcll(mask & ((1ull << lane) - 1ull));
                skey[pos] = k;
            }
            cnt += __popcll(mask);
        }
    }
    __syncthreads();

    float T = 1.f, Cr = 0.f, Cg = 0.f, Cb = 0.f;
    if (cnt > 0 && cnt <= 64) {
        // ---- in-register shfl sort; own key = sorted list entry
        unsigned long long key = (lane < cnt) ? skey[lane] : ~0ull;
        for (int k = 2; k <= 64; k <<= 1)
            for (int j = k >> 1; j >= 1; j >>= 1)
                key = bstage_shfl(key, lane, j, k);
        int gg = (int)((key >> 20) & (NG - 1));
        float4 r0 = rec[gg*3 + 0];
        float4 r1 = rec[gg*3 + 1];
        float4 r2 = rec[gg*3 + 2];
        for (int m = 0; m < cnt; m++) {
            float gpx = rlane(r0.x, m), gpy = rlane(r0.y, m);
            float gA  = rlane(r0.z, m), gB  = rlane(r0.w, m);
            float gC  = rlane(r1.x, m), gop = rlane(r1.y, m);
            float gcr = rlane(r1.z, m), gcg = rlane(r1.w, m);
            float gcb = rlane(r2.x, m);
            float dx = gpx - pixx, dy = gpy - pixy;
            float p2 = fmaf(gA, dx*dx, fmaf(gC, dy*dy, gB*(dx*dy)));
            float e  = __builtin_amdgcn_exp2f(p2);     // power<=0 guaranteed
            float alpha = fminf(gop * e, 0.99f);
            float a2 = (alpha >= (1.f/255.f)) ? alpha : 0.f;
            float w = a2 * T;
            Cr = fmaf(gcr, w, Cr);
            Cg = fmaf(gcg, w, Cg);
            Cb = fmaf(gcb, w, Cb);
            T  = T - a2 * T;
            if ((m & 15) == 15 && __all(T < 1e-4f)) break;
        }
    } else if (cnt > 64) {
        // ---- LDS bitonic sort then chunked blend
        int P = 128;
        while (P < cnt) P <<= 1;
        for (int i2 = cnt + lane; i2 < P; i2 += 64) skey[i2] = ~0ull;
        __syncthreads();
        for (int k = 2; k <= P; k <<= 1) {
            for (int j = k >> 1; j >= 1; j >>= 1) {
                for (int i2 = lane; i2 < P; i2 += 64) {
                    int ixj = i2 ^ j;
                    if (ixj > i2) {
                        bool asc = (i2 & k) == 0;
                        unsigned long long u = skey[i2], v = skey[ixj];
                        if ((u > v) == asc) { skey[i2] = v; skey[ixj] = u; }
                    }
                }
                __syncthreads();
            }
        }
        bool dead = false;
        for (int c = 0; c < cnt && !dead; c += 64) {
            int len = min(64, cnt - c);
            int idx = c + lane;
            int gg = 0;
            if (idx < cnt) gg = (int)((skey[idx] >> 20) & (NG - 1));
            float4 r0 = rec[gg*3 + 0];
            float4 r1 = rec[gg*3 + 1];
            float4 r2 = rec[gg*3 + 2];
            for (int m = 0; m < len; m++) {
                float gpx = rlane(r0.x, m), gpy = rlane(r0.y, m);
                float gA  = rlane(r0.z, m), gB  = rlane(r0.w, m);
                float gC  = rlane(r1.x, m), gop = rlane(r1.y, m);
                float gcr = rlane(r1.z, m), gcg = rlane(r1.w, m);
                float gcb = rlane(r2.x, m);
                float dx = gpx - pixx, dy = gpy - pixy;
                float p2 = fmaf(gA, dx*dx, fmaf(gC, dy*dy, gB*(dx*dy)));
                float e  = __builtin_amdgcn_exp2f(p2);
                float alpha = fminf(gop * e, 0.99f);
                float a2 = (alpha >= (1.f/255.f)) ? alpha : 0.f;
                float w = a2 * T;
                Cr = fmaf(gcr, w, Cr);
                Cg = fmaf(gcg, w, Cg);
                Cb = fmaf(gcb, w, Cb);
                T  = T - a2 * T;
                if ((m & 15) == 15 && __all(T < 1e-4f)) { dead = true; break; }
            }
            if (__all(T < 1e-4f)) dead = true;
        }
    }

    int p = (ty*8 + ly) * W + tx*8 + lx;
    out[p]        = Cr + background[0]*T;
    out[HW + p]   = Cg + background[1]*T;
    out[2*HW + p] = Cb + background[2]*T;
}

// ---------------------------------------------------------------- launcher
extern "C" void kernel_launch(void* const* d_in, const int* in_sizes, int n_in,
                              void* d_out, int out_size, void* d_ws, size_t ws_size,
                              hipStream_t stream) {
    const float* background = (const float*)d_in[0];
    const float* means3D    = (const float*)d_in[1];
    const float* opacities  = (const float*)d_in[2];
    const float* scales     = (const float*)d_in[3];
    const float* rotations  = (const float*)d_in[4];
    const float* shs        = (const float*)d_in[5];
    const float* view_mat   = (const float*)d_in[6];
    const float* proj_mat   = (const float*)d_in[7];
    const float* cam_pos    = (const float*)d_in[8];
    const float* tanx       = (const float*)d_in[9];
    const float* tany       = (const float*)d_in[10];
    const int*   hp         = (const int*)d_in[11];
    const int*   wp         = (const int*)d_in[12];

    int N  = in_sizes[2];        // opacities: (N,1)
    int HW = out_size / 3;
    int W  = 256;                // fixed per problem (H*W == HW)
    int H  = HW / W;
    float* out = (float*)d_out;

    unsigned long long* grec = (unsigned long long*)d_ws;   // NG u64 (8 KB)
    float4* rec = (float4*)(grec + NG);                     // NG*3 float4 (48 KB)

    prep_kernel<<<16, 64, 0, stream>>>(
        means3D, opacities, scales, rotations, shs, view_mat, proj_mat,
        cam_pos, tanx, tany, hp, wp, grec, rec, N);

    int tiles = (W >> 3) * (H >> 3);
    render_kernel<<<tiles, 64, 0, stream>>>(
        grec, rec, background, out, N, W, HW);
}